// Round 19
// baseline (212.928 us; speedup 1.0000x reference)
//
#include <hip/hip_runtime.h>

typedef short bf16x8 __attribute__((ext_vector_type(8)));
typedef unsigned short u16x8 __attribute__((ext_vector_type(8)));
typedef float f32x4 __attribute__((ext_vector_type(4)));
typedef unsigned short u16;

#define MFMA16(a, b, c) __builtin_amdgcn_mfma_f32_16x16x32_bf16((a), (b), (c), 0, 0, 0)
// Full drain before barrier (R4 race lesson).
#define VMCNT0() asm volatile("s_waitcnt vmcnt(0)" ::: "memory")
// Counted wait (T4): allow n per-wave loads to remain in flight.
#define VMCNTN(n) asm volatile("s_waitcnt vmcnt(" #n ")" ::: "memory")

__device__ __forceinline__ u16 bf16_rtn(float f) {
  unsigned u = __float_as_uint(f);
  u += 0x7fffu + ((u >> 16) & 1u);
  return (u16)(u >> 16);
}
__device__ __forceinline__ float bf16_to_f(u16 h) {
  return __uint_as_float(((unsigned)h) << 16);
}
__device__ __forceinline__ void splitf(float f, u16& hi, u16& lo) {
  hi = bf16_rtn(f);
  lo = bf16_rtn(f - bf16_to_f(hi));
}
__device__ __forceinline__ void gload16(const void* g, void* l) {
  __builtin_amdgcn_global_load_lds(
      (const __attribute__((address_space(1))) unsigned int*)g,
      (__attribute__((address_space(3))) unsigned int*)l, 16, 0, 0);
}
__device__ __forceinline__ float exp2_hw(float x) {
  float r;
  asm("v_exp_f32 %0, %1" : "=v"(r) : "v"(x));
  return r;
}
// tanh-form GELU via exp2+rcp (~7 VALU ops vs ~25 for erff; max diff ~3e-4).
__device__ __forceinline__ float gelu_t(float x) {
  float u = x * x;
  float z2 = x * fmaf(u, 0.10294407f, 2.30222726f);
  float den = exp2_hw(z2) + 1.0f;
  float s = __builtin_amdgcn_rcpf(den);
  return fmaf(-x, s, x);
}
// XCD-aware bijective block swizzle (T1). Requires gx*gy % 8 == 0.
__device__ __forceinline__ void swz_bid(int& bx, int& by) {
  int gx = gridDim.x;
  int lin = (int)blockIdx.y * gx + (int)blockIdx.x;
  int cpx = (gx * (int)gridDim.y) >> 3;
  int nl = (lin & 7) * cpx + (lin >> 3);
  bx = nl % gx;
  by = nl / gx;
}

// ------------- fused prep: input converts + ALL weight transposes -------------
__global__ void k_prep(const float* __restrict__ kq, const float* __restrict__ v,
                       const float* __restrict__ Wk, const float* __restrict__ Wq,
                       const float* __restrict__ Wv, const float* __restrict__ W1,
                       const float* __restrict__ W2, u16* __restrict__ kq_hi,
                       u16* __restrict__ v_bf, u16* __restrict__ WkqT_hi,
                       u16* __restrict__ WkqT_lo, u16* __restrict__ WvT,
                       u16* __restrict__ W1T, u16* __restrict__ W2T) {
  __shared__ float tile[32][33];
  int bid = blockIdx.x;
  if (bid < 8192) {
    int i = bid * 256 + threadIdx.x;
    const int N4 = 1 << 20;
    const float4 v4 = (i < N4) ? ((const float4*)kq)[i] : ((const float4*)v)[i - N4];
    ushort4 h;
    h.x = bf16_rtn(v4.x);
    h.y = bf16_rtn(v4.y);
    h.z = bf16_rtn(v4.z);
    h.w = bf16_rtn(v4.w);
    if (i < N4)
      ((ushort4*)kq_hi)[i] = h;
    else
      ((ushort4*)v_bf)[i - N4] = h;
    return;
  }
  int tx = threadIdx.x & 31, ty = threadIdx.x >> 5;
  if (bid < 11264) {  // Wk/Wq/Wv 1024x1024 transposes
    int zz = bid - 8192;
    int z = zz >> 10, rem = zz & 1023;
    int bx = rem & 31, byy = rem >> 5;
    const float* in = (z == 0) ? Wk : (z == 1) ? Wq : Wv;
    int c0 = bx * 32, r0 = byy * 32;
#pragma unroll
    for (int i = 0; i < 4; ++i)
      tile[ty + i * 8][tx] = in[(size_t)(r0 + ty + i * 8) * 1024 + c0 + tx];
    __syncthreads();
#pragma unroll
    for (int i = 0; i < 4; ++i) {
      float vv = tile[tx][ty + i * 8];
      size_t o = (size_t)(c0 + ty + i * 8) * 1024 + r0 + tx;
      if (z < 2) {
        u16 h, l;
        splitf(vv, h, l);
        WkqT_hi[(size_t)z * 1048576 + o] = h;
        WkqT_lo[(size_t)z * 1048576 + o] = l;
      } else {
        WvT[o] = bf16_rtn(vv);
      }
    }
    return;
  }
  // W1 (1024x4096) / W2 (4096x1024) transposes
  int zz = bid - 11264;
  int z = zz >> 12, rem = zz & 4095;
  const float* in = z ? W2 : W1;
  u16* outp = z ? W2T : W1T;
  int R = z ? 4096 : 1024, C = z ? 1024 : 4096;
  int bx = z ? (rem & 31) : (rem & 127);
  int byy = z ? (rem >> 5) : (rem >> 7);
  int c0 = bx * 32, r0 = byy * 32;
#pragma unroll
  for (int i = 0; i < 4; ++i)
    tile[ty + i * 8][tx] = in[(size_t)(r0 + ty + i * 8) * C + c0 + tx];
  __syncthreads();
#pragma unroll
  for (int i = 0; i < 4; ++i)
    outp[(size_t)(c0 + ty + i * 8) * R + r0 + tx] = bf16_rtn(tile[tx][ty + i * 8]);
}

// ------------- non-split GEMM: BM=128, BN in {64,128} -------------
// BK=64, XOR-swizzled LDS, 3-buffer depth-2, counted vmcnt.
// OUT: 0 = fp32 row-major, 1 = bf16 row-major, 5 = V into swizzled KV slab.
template <int GELU, int OUT, int BN>
__global__ __launch_bounds__(256) void k_gemm(
    const u16* __restrict__ A, const u16* __restrict__ B,
    const float* __restrict__ bias, void* __restrict__ C0,
    int M, int Nc, int K) {
  const int NB = BN / 32;
  const int BUFE = 8192 + BN * 64;
  __shared__ u16 sm[3 * BUFE];

  int bx, by;
  swz_bid(bx, by);
  int m0 = by * 128, n0 = bx * BN;
  int t = threadIdx.x, lane = t & 63, w = t >> 6;
  int wr = (w >> 1) * 64, wc = (w & 1) * (BN / 2);
  int li = lane & 15, g = lane >> 4;
  int lrow = lane >> 3, lcg = lane & 7;

  f32x4 acc[4][NB] = {};
  const int nk = K >> 6;

  auto stage = [&](int kb, int buf) {
    int k0 = kb * 64;
    u16* base = sm + buf * BUFE;
#pragma unroll
    for (int j = 0; j < 4; ++j) {
      int jj = w * 4 + j;
      int row = jj * 8 + lrow;
      int cg = lcg ^ (row & 7);
      gload16(A + (size_t)(m0 + row) * K + k0 + cg * 8, base + jj * 512);
    }
#pragma unroll
    for (int j = 0; j < NB; ++j) {
      int jj = w * NB + j;
      int row = jj * 8 + lrow;
      int cg = lcg ^ (row & 7);
      gload16(B + (size_t)(n0 + row) * K + k0 + cg * 8, base + 8192 + jj * 512);
    }
  };

  stage(0, 0);
  stage(1, 1);
  if (NB == 4) { VMCNTN(8); } else { VMCNTN(6); }
  __syncthreads();

  int cur = 0;
  for (int kb = 0; kb < nk; ++kb) {
    int stb = cur + 2;
    if (stb >= 3) stb -= 3;
    if (kb + 2 < nk) stage(kb + 2, stb);

    const u16* bs = sm + cur * BUFE;
#pragma unroll
    for (int kk = 0; kk < 2; ++kk) {
      bf16x8 af[4], bf[NB];
#pragma unroll
      for (int i = 0; i < 4; ++i) {
        int row = wr + i * 16 + li;
        af[i] = *(const bf16x8*)&bs[row * 64 + (((kk * 4 + g) ^ (li & 7)) << 3)];
      }
#pragma unroll
      for (int b = 0; b < NB; ++b) {
        int row = wc + b * 16 + li;
        bf[b] = *(const bf16x8*)&bs[8192 + row * 64 + (((kk * 4 + g) ^ (li & 7)) << 3)];
      }
#pragma unroll
      for (int a = 0; a < 4; ++a)
#pragma unroll
        for (int b = 0; b < NB; ++b) acc[a][b] = MFMA16(af[a], bf[b], acc[a][b]);
    }
    if (kb + 2 < nk) {
      if (NB == 4) { VMCNTN(8); } else { VMCNTN(6); }
    } else {
      VMCNT0();
    }
    __syncthreads();
    cur = (cur == 2) ? 0 : cur + 1;
  }

#pragma unroll
  for (int a = 0; a < 4; ++a)
#pragma unroll
    for (int b = 0; b < NB; ++b)
#pragma unroll
      for (int r = 0; r < 4; ++r) {
        int row = m0 + wr + a * 16 + g * 4 + r;
        int col = n0 + wc + b * 16 + li;
        float v = acc[a][b][r] + bias[col];
        if (GELU) v = gelu_t(v);
        if (OUT == 0) {
          ((float*)C0)[(size_t)row * Nc + col] = v;
        } else if (OUT == 1) {
          ((u16*)C0)[(size_t)row * Nc + col] = bf16_rtn(v);
        } else if (OUT == 5) {
          int nn = row >> 11, tt = row & 2047, kbb = tt >> 6, tr = tt & 63;
          int hq = col >> 6, d = col & 63;
          size_t base = (((size_t)nn * 16 + hq) * 32 + kbb) * 8192 + 4096;
          size_t ov = base + d * 64 + (tr & 7) + (((tr >> 3) ^ (d & 7)) << 3);
          ((u16*)C0)[ov] = bf16_rtn(v);
        }
      }
}

// ------------- KQ projection GEMM: BM=128 x BN=64, BK=64, 2-pass split-B -------------
// Fixes k_gemm_s's half-line staging (BK=32 -> 64B/row fetches wasted half of
// every 128B line). Full-line BK=64 staging with the proven lcg^(row&7)
// swizzle; 2-buffer 64KB LDS (2 blocks/CU); drain-at-tile-end (R12-proven:
// 32-MFMA compute covers the prefetch). acc = Ah*Bh + Ah*Bl.
// Epilogue: col<1024 -> K bf16 into swizzled KV slab; col>=1024 -> Q
// (pre-scaled by log2e) split hi/lo head-major [n,h,t,d].
__global__ __launch_bounds__(256) void k_gemm_kq(
    const u16* __restrict__ A, const u16* __restrict__ Bh,
    const u16* __restrict__ Bl, const float* __restrict__ bias,
    const float* __restrict__ bias2, void* __restrict__ C0,
    void* __restrict__ C1, void* __restrict__ C2, int M, int Nc, int K) {
  const int BUFE = 16384;       // u16: A[128][64] | Bh[64][64] | Bl[64][64]
  __shared__ u16 sm[2 * BUFE];  // 64 KB

  int bx, by;
  swz_bid(bx, by);
  int m0 = by * 128, n0 = bx * 64;
  int t = threadIdx.x, lane = t & 63, w = t >> 6;
  int wr = (w >> 1) * 64, wc = (w & 1) * 32;
  int li = lane & 15, g = lane >> 4;
  int lrow = lane >> 3, lcg = lane & 7;

  f32x4 acc[4][2] = {};
  const int nk = K >> 6;

  auto stage = [&](int kb, int buf) {
    int k0 = kb * 64;
    u16* base = sm + buf * BUFE;
#pragma unroll
    for (int j = 0; j < 4; ++j) {  // A: 16 calls, 128 rows
      int jj = w * 4 + j;
      int row = jj * 8 + lrow;
      int cg = lcg ^ (row & 7);
      gload16(A + (size_t)(m0 + row) * K + k0 + cg * 8, base + jj * 512);
    }
#pragma unroll
    for (int j = 0; j < 2; ++j) {  // Bh + Bl: 8 calls each, 64 rows
      int jj = w * 2 + j;
      int row = jj * 8 + lrow;
      int cg = lcg ^ (row & 7);
      gload16(Bh + (size_t)(n0 + row) * K + k0 + cg * 8, base + 8192 + jj * 512);
      gload16(Bl + (size_t)(n0 + row) * K + k0 + cg * 8, base + 12288 + jj * 512);
    }
  };

  stage(0, 0);
  VMCNT0();
  __syncthreads();

  int cur = 0;
  for (int kb = 0; kb < nk; ++kb) {
    if (kb + 1 < nk) stage(kb + 1, cur ^ 1);  // issued at tile top

    const u16* bs = sm + cur * BUFE;
#pragma unroll
    for (int kk = 0; kk < 2; ++kk) {
      bf16x8 af[4], bh[2], bl[2];
#pragma unroll
      for (int i = 0; i < 4; ++i) {
        int row = wr + i * 16 + li;
        af[i] = *(const bf16x8*)&bs[row * 64 + (((kk * 4 + g) ^ (li & 7)) << 3)];
      }
#pragma unroll
      for (int b = 0; b < 2; ++b) {
        int row = wc + b * 16 + li;
        bh[b] = *(const bf16x8*)&bs[8192 + row * 64 + (((kk * 4 + g) ^ (li & 7)) << 3)];
        bl[b] = *(const bf16x8*)&bs[12288 + row * 64 + (((kk * 4 + g) ^ (li & 7)) << 3)];
      }
#pragma unroll
      for (int a = 0; a < 4; ++a)
#pragma unroll
        for (int b = 0; b < 2; ++b) {
          acc[a][b] = MFMA16(af[a], bh[b], acc[a][b]);
          acc[a][b] = MFMA16(af[a], bl[b], acc[a][b]);
        }
    }
    VMCNT0();  // 2-buffer: next tile's loads must land (compute covered latency)
    __syncthreads();
    cur ^= 1;
  }

#pragma unroll
  for (int a = 0; a < 4; ++a)
#pragma unroll
    for (int b = 0; b < 2; ++b)
#pragma unroll
      for (int r = 0; r < 4; ++r) {
        int row = m0 + wr + a * 16 + g * 4 + r;
        int col = n0 + wc + b * 16 + li;
        float bb = col < 1024 ? bias[col] : bias2[col - 1024];
        float v = acc[a][b][r] + bb;
        if (col < 1024) {  // K -> swizzled KV slab (single bf16 rounding)
          int nn = row >> 11, tt = row & 2047, kbb = tt >> 6, tr = tt & 63;
          int hq = col >> 6, d = col & 63, ks = d >> 5, dc = d & 31;
          size_t base = (((size_t)nn * 16 + hq) * 32 + kbb) * 8192;
          size_t oh = base + ks * 2048 + tr * 32 + (dc & 7) +
                      (((dc >> 3) ^ ((tr >> 1) & 3)) << 3);
          ((u16*)C0)[oh] = bf16_rtn(v);
        } else {  // Q (pre-scaled by log2e) -> split hi/lo head-major
          int cq = col - 1024;
          float vq = v * 1.4426950408889634f;
          u16 hh, ll;
          splitf(vq, hh, ll);
          size_t off = (((size_t)(row >> 11) * 16 + (cq >> 6)) * 2048 + (row & 2047)) * 64 + (cq & 63);
          ((u16*)C1)[off] = hh;
          ((u16*)C2)[off] = ll;
        }
      }
}

// ------------- big-tile GEMM: 256x256, 8 waves, BK=64 (R12-proven) -------------
template <int GELU, int OUT>
__global__ __launch_bounds__(512, 1) void k_gemm2(
    const u16* __restrict__ A, const u16* __restrict__ B,
    const float* __restrict__ bias, void* __restrict__ C0,
    int M, int Nc, int K) {
  const int BUFE = 32768;
  __shared__ u16 sm[2 * BUFE];  // 128 KB

  int bx, by;
  swz_bid(bx, by);
  int m0 = by * 256, n0 = bx * 256;
  int t = threadIdx.x, lane = t & 63, w = t >> 6;
  int wr = (w >> 2) * 128, wc = (w & 3) * 64;
  int li = lane & 15, g = lane >> 4;
  int lrow = lane >> 3, lcg = lane & 7;

  f32x4 acc[8][4] = {};
  const int nk = K >> 6;

  auto stage = [&](int kb, int buf) {
    int k0 = kb * 64;
    u16* base = sm + buf * BUFE;
#pragma unroll
    for (int j = 0; j < 4; ++j) {
      int jj = w * 4 + j;
      int row = jj * 8 + lrow;
      int cg = lcg ^ (row & 7);
      gload16(A + (size_t)(m0 + row) * K + k0 + cg * 8, base + jj * 512);
      gload16(B + (size_t)(n0 + row) * K + k0 + cg * 8, base + 16384 + jj * 512);
    }
  };

  stage(0, 0);
  VMCNT0();
  __syncthreads();

  int cur = 0;
  for (int kb = 0; kb < nk; ++kb) {
    if (kb + 1 < nk) stage(kb + 1, cur ^ 1);

    const u16* bs = sm + cur * BUFE;
#pragma unroll
    for (int kk = 0; kk < 2; ++kk) {
      bf16x8 af[8], bf[4];
#pragma unroll
      for (int i = 0; i < 8; ++i) {
        int row = wr + i * 16 + li;
        af[i] = *(const bf16x8*)&bs[row * 64 + (((kk * 4 + g) ^ (li & 7)) << 3)];
      }
#pragma unroll
      for (int b = 0; b < 4; ++b) {
        int row = wc + b * 16 + li;
        bf[b] = *(const bf16x8*)&bs[16384 + row * 64 + (((kk * 4 + g) ^ (li & 7)) << 3)];
      }
#pragma unroll
      for (int a = 0; a < 8; ++a)
#pragma unroll
        for (int b = 0; b < 4; ++b) acc[a][b] = MFMA16(af[a], bf[b], acc[a][b]);
    }
    VMCNT0();
    __syncthreads();
    cur ^= 1;
  }

#pragma unroll
  for (int a = 0; a < 8; ++a)
#pragma unroll
    for (int b = 0; b < 4; ++b)
#pragma unroll
      for (int r = 0; r < 4; ++r) {
        int row = m0 + wr + a * 16 + g * 4 + r;
        int col = n0 + wc + b * 16 + li;
        float v = acc[a][b][r] + bias[col];
        if (GELU) v = gelu_t(v);
        if (OUT == 1)
          ((u16*)C0)[(size_t)row * Nc + col] = bf16_rtn(v);
        else
          ((float*)C0)[(size_t)row * Nc + col] = v;
      }
}

// ------------- flash attention, strictly-causal + [0,0], no 1/sqrt(d) -------------
// R16-proven (51.4 us): QBLK=128, 8 waves, grid (32,16) largest-first,
// 3-buf counted vmcnt(2), unnormalized softmax, 67.5KB LDS -> 2 blocks/CU.
__global__ __launch_bounds__(512) void k_attn(
    const u16* __restrict__ Qh, const u16* __restrict__ Ql,
    const u16* __restrict__ KV, u16* __restrict__ out) {
  const int T = 2048, HD = 64, H = 16, E = 1024;
  int hc = blockIdx.x;
  int h = hc & 15, n = hc >> 4;
  int qq = 15 - (int)blockIdx.y;
  __shared__ u16 KB[3][8192];
  __shared__ u16 P[2][128][36];
  int t = threadIdx.x, lane = t & 63, w = t >> 6;
  int li = lane & 15, g = lane >> 4;

  const size_t nh = (size_t)n * H + h;
  const u16* qhb = Qh + (nh * 2048 + (size_t)qq * 128) * 64;
  const u16* qlb = Ql + (nh * 2048 + (size_t)qq * 128) * 64;
  const u16* kvb = KV + nh * 32 * 8192;

  bf16x8 qh[2], ql[2];
#pragma unroll
  for (int ks = 0; ks < 2; ++ks) {
    qh[ks] = *(const bf16x8*)&qhb[(w * 16 + li) * 64 + ks * 32 + g * 8];
    ql[ks] = *(const bf16x8*)&qlb[(w * 16 + li) * 64 + ks * 32 + g * 8];
  }

#pragma unroll
  for (int j = 0; j < 2; ++j)
    gload16(kvb + (w * 2 + j) * 512 + lane * 8, &KB[0][(w * 2 + j) * 512]);
#pragma unroll
  for (int j = 0; j < 2; ++j)
    gload16(kvb + 8192 + (w * 2 + j) * 512 + lane * 8, &KB[1][(w * 2 + j) * 512]);
  VMCNTN(2);
  __syncthreads();

  float lr[4] = {0.f, 0.f, 0.f, 0.f};
  f32x4 O[4] = {};
  int cur = 0;
  const int nkb = 2 * qq + 2;

  for (int kb = 0; kb < nkb; ++kb) {
    int stb = cur + 2;
    if (stb >= 3) stb -= 3;
    if (kb + 2 < nkb) {
      const u16* src = kvb + (size_t)(kb + 2) * 8192 + (w * 2) * 512 + lane * 8;
#pragma unroll
      for (int j = 0; j < 2; ++j)
        gload16(src + j * 512, &KB[stb][(w * 2 + j) * 512]);
    }

    f32x4 s[4] = {};
#pragma unroll
    for (int ks = 0; ks < 2; ++ks)
#pragma unroll
      for (int c = 0; c < 4; ++c) {
        int jr = c * 16 + li;
        int sw = (jr >> 1) & 3;
        bf16x8 kh = *(const bf16x8*)&KB[cur][ks * 2048 + jr * 32 + ((g ^ sw) << 3)];
        s[c] = MFMA16(qh[ks], kh, s[c]);
        s[c] = MFMA16(ql[ks], kh, s[c]);
      }

    if (kb >= 2 * qq) {
#pragma unroll
      for (int c = 0; c < 4; ++c)
#pragma unroll
        for (int r = 0; r < 4; ++r) {
          int i = qq * 128 + w * 16 + g * 4 + r;
          int j = kb * 64 + c * 16 + li;
          if (!(j < i || (i == 0 && j == 0))) s[c][r] = -INFINITY;
        }
    }

#pragma unroll
    for (int c = 0; c < 4; ++c)
#pragma unroll
      for (int r = 0; r < 4; ++r) {
        float p = exp2_hw(s[c][r]);
        s[c][r] = p;
        lr[r] += p;
      }

#pragma unroll
    for (int c = 0; c < 4; ++c)
#pragma unroll
      for (int r = 0; r < 4; ++r)
        P[c >> 1][w * 16 + g * 4 + r][(c & 1) * 16 + li] = bf16_rtn(s[c][r]);

#pragma unroll
    for (int ks = 0; ks < 2; ++ks) {
      bf16x8 pa = *(const bf16x8*)&P[ks][w * 16 + li][g * 8];
#pragma unroll
      for (int c = 0; c < 4; ++c) {
        int d = c * 16 + li;
        int tc = ks * 4 + g;
        bf16x8 vb = *(const bf16x8*)&KB[cur][4096 + d * 64 + ((tc ^ (d & 7)) << 3)];
        O[c] = MFMA16(pa, vb, O[c]);
      }
    }
    if (kb + 2 < nkb) {
      VMCNTN(2);
    } else {
      VMCNT0();
    }
    __syncthreads();
    cur = (cur == 2) ? 0 : cur + 1;
  }

#pragma unroll
  for (int off = 1; off < 16; off <<= 1)
#pragma unroll
    for (int r = 0; r < 4; ++r) lr[r] += __shfl_xor(lr[r], off, 16);

#pragma unroll
  for (int c = 0; c < 4; ++c)
#pragma unroll
    for (int r = 0; r < 4; ++r) {
      float v = O[c][r] / lr[r];
      size_t row = (size_t)n * T + qq * 128 + w * 16 + g * 4 + r;
      out[row * E + h * HD + c * 16 + li] = bf16_rtn(v);
    }
}

// ---------------------------------------------------------------------------
extern "C" void kernel_launch(void* const* d_in, const int* in_sizes, int n_in,
                              void* d_out, int out_size, void* d_ws, size_t ws_size,
                              hipStream_t stream) {
  const float* kq = (const float*)d_in[0];
  const float* v = (const float*)d_in[1];
  const float* Wk = (const float*)d_in[2];
  const float* bk = (const float*)d_in[3];
  const float* Wq = (const float*)d_in[4];
  const float* bq = (const float*)d_in[5];
  const float* Wv = (const float*)d_in[6];
  const float* bv = (const float*)d_in[7];
  const float* W1 = (const float*)d_in[8];
  const float* b1 = (const float*)d_in[9];
  const float* W2 = (const float*)d_in[10];
  const float* b2 = (const float*)d_in[11];
  float* outp = (float*)d_out;

  char* ws = (char*)d_ws;
  u16* kq_hi = (u16*)(ws + 0);
  u16* v_bf = (u16*)(ws + 8388608);
  u16* hbuf = (u16*)(ws + 0);  // 32MB, aliases kq_hi/v_bf after attention
  u16* WkqT_hi = (u16*)(ws + 33554432);  // 4MB: [WkT | WqT]
  u16* WkqT_lo = (u16*)(ws + 37748736);  // 4MB
  u16* WvT = (u16*)(ws + 41943040);
  u16* W1T = (u16*)(ws + 44040192);
  u16* W2T = (u16*)(ws + 52428800);
  u16* Qh = (u16*)(ws + 60817408);
  u16* Ql = (u16*)(ws + 69206016);
  u16* KV = (u16*)(ws + 77594624);  // 16MB: 1024 slabs x 16KB (K hi + V)
  u16* attn_o = (u16*)(ws + 102760448);
  // total: 111,149,056 bytes

  // --- all prep in ONE launch (cvt + 5 weight transposes) ---
  k_prep<<<19456, 256, 0, stream>>>(kq, v, Wk, Wq, Wv, W1, W2, kq_hi, v_bf,
                                    WkqT_hi, WkqT_lo, WvT, W1T, W2T);

  // --- fused K|Q projection: BK=64 full-line staging, 2-buffer, 1024 blocks ---
  k_gemm_kq<<<dim3(32, 32), 256, 0, stream>>>(
      kq_hi, WkqT_hi, WkqT_lo, bk, bq, KV, Qh, Ql, 4096, 2048, 1024);
  // --- V projection ---
  k_gemm<0, 5, 64><<<dim3(16, 32), 256, 0, stream>>>(
      v_bf, WvT, bv, KV, 4096, 1024, 1024);

  // --- attention (R16-proven) ---
  k_attn<<<dim3(32, 16), 512, 0, stream>>>(Qh, Ql, KV, attn_o);

  // --- FFN ---
  k_gemm2<1, 1><<<dim3(16, 16), 512, 0, stream>>>(
      attn_o, W1T, b1, hbuf, 4096, 4096, 1024);
  // FFN2: BN=64 -> 512 blocks (2/CU co-residency hides the tile-boundary wait)
  k_gemm<0, 0, 64><<<dim3(16, 32), 256, 0, stream>>>(
      hbuf, W2T, b2, outp, 4096, 1024, 4096);
}

// Round 20
// 208.200 us; speedup vs baseline: 1.0227x; 1.0227x over previous
//
#include <hip/hip_runtime.h>

typedef short bf16x8 __attribute__((ext_vector_type(8)));
typedef unsigned short u16x8 __attribute__((ext_vector_type(8)));
typedef float f32x4 __attribute__((ext_vector_type(4)));
typedef unsigned short u16;

#define MFMA16(a, b, c) __builtin_amdgcn_mfma_f32_16x16x32_bf16((a), (b), (c), 0, 0, 0)
// Full drain before barrier (R4 race lesson).
#define VMCNT0() asm volatile("s_waitcnt vmcnt(0)" ::: "memory")
// Counted wait (T4): allow n per-wave loads to remain in flight.
#define VMCNTN(n) asm volatile("s_waitcnt vmcnt(" #n ")" ::: "memory")

__device__ __forceinline__ u16 bf16_rtn(float f) {
  unsigned u = __float_as_uint(f);
  u += 0x7fffu + ((u >> 16) & 1u);
  return (u16)(u >> 16);
}
__device__ __forceinline__ float bf16_to_f(u16 h) {
  return __uint_as_float(((unsigned)h) << 16);
}
__device__ __forceinline__ void splitf(float f, u16& hi, u16& lo) {
  hi = bf16_rtn(f);
  lo = bf16_rtn(f - bf16_to_f(hi));
}
__device__ __forceinline__ void gload16(const void* g, void* l) {
  __builtin_amdgcn_global_load_lds(
      (const __attribute__((address_space(1))) unsigned int*)g,
      (__attribute__((address_space(3))) unsigned int*)l, 16, 0, 0);
}
__device__ __forceinline__ float exp2_hw(float x) {
  float r;
  asm("v_exp_f32 %0, %1" : "=v"(r) : "v"(x));
  return r;
}
// tanh-form GELU via exp2+rcp (~7 VALU ops vs ~25 for erff; max diff ~3e-4).
__device__ __forceinline__ float gelu_t(float x) {
  float u = x * x;
  float z2 = x * fmaf(u, 0.10294407f, 2.30222726f);
  float den = exp2_hw(z2) + 1.0f;
  float s = __builtin_amdgcn_rcpf(den);
  return fmaf(-x, s, x);
}
// XCD-aware bijective block swizzle (T1). Requires gx*gy % 8 == 0.
__device__ __forceinline__ void swz_bid(int& bx, int& by) {
  int gx = gridDim.x;
  int lin = (int)blockIdx.y * gx + (int)blockIdx.x;
  int cpx = (gx * (int)gridDim.y) >> 3;
  int nl = (lin & 7) * cpx + (lin >> 3);
  bx = nl % gx;
  by = nl / gx;
}

// ------------- fused prep: input converts + ALL weight transposes -------------
// blocks [0,8192):        kq -> bf16, v -> bf16 (float4 vectorized)
// blocks [8192,11264):    Wk/Wq -> WkqT hi+lo, Wv -> WvT   (32x32 tiles)
// blocks [11264,19456):   W1 -> W1T, W2 -> W2T             (32x32 tiles)
__global__ void k_prep(const float* __restrict__ kq, const float* __restrict__ v,
                       const float* __restrict__ Wk, const float* __restrict__ Wq,
                       const float* __restrict__ Wv, const float* __restrict__ W1,
                       const float* __restrict__ W2, u16* __restrict__ kq_hi,
                       u16* __restrict__ v_bf, u16* __restrict__ WkqT_hi,
                       u16* __restrict__ WkqT_lo, u16* __restrict__ WvT,
                       u16* __restrict__ W1T, u16* __restrict__ W2T) {
  __shared__ float tile[32][33];
  int bid = blockIdx.x;
  if (bid < 8192) {
    int i = bid * 256 + threadIdx.x;
    const int N4 = 1 << 20;
    const float4 v4 = (i < N4) ? ((const float4*)kq)[i] : ((const float4*)v)[i - N4];
    ushort4 h;
    h.x = bf16_rtn(v4.x);
    h.y = bf16_rtn(v4.y);
    h.z = bf16_rtn(v4.z);
    h.w = bf16_rtn(v4.w);
    if (i < N4)
      ((ushort4*)kq_hi)[i] = h;
    else
      ((ushort4*)v_bf)[i - N4] = h;
    return;
  }
  int tx = threadIdx.x & 31, ty = threadIdx.x >> 5;
  if (bid < 11264) {  // Wk/Wq/Wv 1024x1024 transposes
    int zz = bid - 8192;
    int z = zz >> 10, rem = zz & 1023;
    int bx = rem & 31, byy = rem >> 5;
    const float* in = (z == 0) ? Wk : (z == 1) ? Wq : Wv;
    int c0 = bx * 32, r0 = byy * 32;
#pragma unroll
    for (int i = 0; i < 4; ++i)
      tile[ty + i * 8][tx] = in[(size_t)(r0 + ty + i * 8) * 1024 + c0 + tx];
    __syncthreads();
#pragma unroll
    for (int i = 0; i < 4; ++i) {
      float vv = tile[tx][ty + i * 8];
      size_t o = (size_t)(c0 + ty + i * 8) * 1024 + r0 + tx;
      if (z < 2) {
        u16 h, l;
        splitf(vv, h, l);
        WkqT_hi[(size_t)z * 1048576 + o] = h;
        WkqT_lo[(size_t)z * 1048576 + o] = l;
      } else {
        WvT[o] = bf16_rtn(vv);
      }
    }
    return;
  }
  // W1 (1024x4096) / W2 (4096x1024) transposes
  int zz = bid - 11264;
  int z = zz >> 12, rem = zz & 4095;
  const float* in = z ? W2 : W1;
  u16* outp = z ? W2T : W1T;
  int R = z ? 4096 : 1024, C = z ? 1024 : 4096;
  int bx = z ? (rem & 31) : (rem & 127);
  int byy = z ? (rem >> 5) : (rem >> 7);
  int c0 = bx * 32, r0 = byy * 32;
#pragma unroll
  for (int i = 0; i < 4; ++i)
    tile[ty + i * 8][tx] = in[(size_t)(r0 + ty + i * 8) * C + c0 + tx];
  __syncthreads();
#pragma unroll
  for (int i = 0; i < 4; ++i)
    outp[(size_t)(c0 + ty + i * 8) * R + r0 + tx] = bf16_rtn(tile[tx][ty + i * 8]);
}

// ------------- non-split GEMM: BM=128, BN in {64,128} -------------
// BK=64, XOR-swizzled LDS, 3-buffer depth-2, counted vmcnt.
// OUT: 0 = fp32 row-major, 1 = bf16 row-major, 5 = V into swizzled KV slab.
template <int GELU, int OUT, int BN>
__global__ __launch_bounds__(256) void k_gemm(
    const u16* __restrict__ A, const u16* __restrict__ B,
    const float* __restrict__ bias, void* __restrict__ C0,
    int M, int Nc, int K) {
  const int NB = BN / 32;
  const int BUFE = 8192 + BN * 64;
  __shared__ u16 sm[3 * BUFE];

  int bx, by;
  swz_bid(bx, by);
  int m0 = by * 128, n0 = bx * BN;
  int t = threadIdx.x, lane = t & 63, w = t >> 6;
  int wr = (w >> 1) * 64, wc = (w & 1) * (BN / 2);
  int li = lane & 15, g = lane >> 4;
  int lrow = lane >> 3, lcg = lane & 7;

  f32x4 acc[4][NB] = {};
  const int nk = K >> 6;

  auto stage = [&](int kb, int buf) {
    int k0 = kb * 64;
    u16* base = sm + buf * BUFE;
#pragma unroll
    for (int j = 0; j < 4; ++j) {
      int jj = w * 4 + j;
      int row = jj * 8 + lrow;
      int cg = lcg ^ (row & 7);
      gload16(A + (size_t)(m0 + row) * K + k0 + cg * 8, base + jj * 512);
    }
#pragma unroll
    for (int j = 0; j < NB; ++j) {
      int jj = w * NB + j;
      int row = jj * 8 + lrow;
      int cg = lcg ^ (row & 7);
      gload16(B + (size_t)(n0 + row) * K + k0 + cg * 8, base + 8192 + jj * 512);
    }
  };

  stage(0, 0);
  stage(1, 1);
  if (NB == 4) { VMCNTN(8); } else { VMCNTN(6); }
  __syncthreads();

  int cur = 0;
  for (int kb = 0; kb < nk; ++kb) {
    int stb = cur + 2;
    if (stb >= 3) stb -= 3;
    if (kb + 2 < nk) stage(kb + 2, stb);

    const u16* bs = sm + cur * BUFE;
#pragma unroll
    for (int kk = 0; kk < 2; ++kk) {
      bf16x8 af[4], bf[NB];
#pragma unroll
      for (int i = 0; i < 4; ++i) {
        int row = wr + i * 16 + li;
        af[i] = *(const bf16x8*)&bs[row * 64 + (((kk * 4 + g) ^ (li & 7)) << 3)];
      }
#pragma unroll
      for (int b = 0; b < NB; ++b) {
        int row = wc + b * 16 + li;
        bf[b] = *(const bf16x8*)&bs[8192 + row * 64 + (((kk * 4 + g) ^ (li & 7)) << 3)];
      }
#pragma unroll
      for (int a = 0; a < 4; ++a)
#pragma unroll
        for (int b = 0; b < NB; ++b) acc[a][b] = MFMA16(af[a], bf[b], acc[a][b]);
    }
    if (kb + 2 < nk) {
      if (NB == 4) { VMCNTN(8); } else { VMCNTN(6); }
    } else {
      VMCNT0();
    }
    __syncthreads();
    cur = (cur == 2) ? 0 : cur + 1;
  }

#pragma unroll
  for (int a = 0; a < 4; ++a)
#pragma unroll
    for (int b = 0; b < NB; ++b)
#pragma unroll
      for (int r = 0; r < 4; ++r) {
        int row = m0 + wr + a * 16 + g * 4 + r;
        int col = n0 + wc + b * 16 + li;
        float v = acc[a][b][r] + bias[col];
        if (GELU) v = gelu_t(v);
        if (OUT == 0) {
          ((float*)C0)[(size_t)row * Nc + col] = v;
        } else if (OUT == 1) {
          ((u16*)C0)[(size_t)row * Nc + col] = bf16_rtn(v);
        } else if (OUT == 5) {
          int nn = row >> 11, tt = row & 2047, kbb = tt >> 6, tr = tt & 63;
          int hq = col >> 6, d = col & 63;
          size_t base = (((size_t)nn * 16 + hq) * 32 + kbb) * 8192 + 4096;
          size_t ov = base + d * 64 + (tr & 7) + (((tr >> 3) ^ (d & 7)) << 3);
          ((u16*)C0)[ov] = bf16_rtn(v);
        }
      }
}

// ------------- big-tile GEMM: 256x256, 8 waves, BK=64 (R12-proven) -------------
template <int GELU, int OUT>
__global__ __launch_bounds__(512, 1) void k_gemm2(
    const u16* __restrict__ A, const u16* __restrict__ B,
    const float* __restrict__ bias, void* __restrict__ C0,
    int M, int Nc, int K) {
  const int BUFE = 32768;
  __shared__ u16 sm[2 * BUFE];  // 128 KB

  int bx, by;
  swz_bid(bx, by);
  int m0 = by * 256, n0 = bx * 256;
  int t = threadIdx.x, lane = t & 63, w = t >> 6;
  int wr = (w >> 2) * 128, wc = (w & 3) * 64;
  int li = lane & 15, g = lane >> 4;
  int lrow = lane >> 3, lcg = lane & 7;

  f32x4 acc[8][4] = {};
  const int nk = K >> 6;

  auto stage = [&](int kb, int buf) {
    int k0 = kb * 64;
    u16* base = sm + buf * BUFE;
#pragma unroll
    for (int j = 0; j < 4; ++j) {
      int jj = w * 4 + j;
      int row = jj * 8 + lrow;
      int cg = lcg ^ (row & 7);
      gload16(A + (size_t)(m0 + row) * K + k0 + cg * 8, base + jj * 512);
      gload16(B + (size_t)(n0 + row) * K + k0 + cg * 8, base + 16384 + jj * 512);
    }
  };

  stage(0, 0);
  VMCNT0();
  __syncthreads();

  int cur = 0;
  for (int kb = 0; kb < nk; ++kb) {
    if (kb + 1 < nk) stage(kb + 1, cur ^ 1);

    const u16* bs = sm + cur * BUFE;
#pragma unroll
    for (int kk = 0; kk < 2; ++kk) {
      bf16x8 af[8], bf[4];
#pragma unroll
      for (int i = 0; i < 8; ++i) {
        int row = wr + i * 16 + li;
        af[i] = *(const bf16x8*)&bs[row * 64 + (((kk * 4 + g) ^ (li & 7)) << 3)];
      }
#pragma unroll
      for (int b = 0; b < 4; ++b) {
        int row = wc + b * 16 + li;
        bf[b] = *(const bf16x8*)&bs[16384 + row * 64 + (((kk * 4 + g) ^ (li & 7)) << 3)];
      }
#pragma unroll
      for (int a = 0; a < 8; ++a)
#pragma unroll
        for (int b = 0; b < 4; ++b) acc[a][b] = MFMA16(af[a], bf[b], acc[a][b]);
    }
    VMCNT0();
    __syncthreads();
    cur ^= 1;
  }

#pragma unroll
  for (int a = 0; a < 8; ++a)
#pragma unroll
    for (int b = 0; b < 4; ++b)
#pragma unroll
      for (int r = 0; r < 4; ++r) {
        int row = m0 + wr + a * 16 + g * 4 + r;
        int col = n0 + wc + b * 16 + li;
        float v = acc[a][b][r] + bias[col];
        if (GELU) v = gelu_t(v);
        if (OUT == 1)
          ((u16*)C0)[(size_t)row * Nc + col] = bf16_rtn(v);
        else
          ((float*)C0)[(size_t)row * Nc + col] = v;
      }
}

// ------------- 2-pass split GEMM (K|Q fused projection) -------------
__global__ __launch_bounds__(256) void k_gemm_s(
    const u16* __restrict__ Ahi, const u16* __restrict__ Bhi,
    const u16* __restrict__ Blo, const float* __restrict__ bias,
    const float* __restrict__ bias2, void* __restrict__ C0,
    void* __restrict__ C1, void* __restrict__ C2, int M, int Nc, int K) {
  const int BUFE = 12288;
  __shared__ u16 sm[3 * BUFE];

  int bx, by;
  swz_bid(bx, by);
  int m0 = by * 128, n0 = bx * 128;
  int t = threadIdx.x, lane = t & 63, w = t >> 6;
  int wr = (w >> 1) * 64, wc = (w & 1) * 64;
  int li = lane & 15, g = lane >> 4;
  int srow = lane >> 2;
  int sc = ((lane & 3) ^ ((srow >> 1) & 3)) * 8;

  f32x4 acc[4][4] = {};
  const int nk = K >> 5;

  auto stage = [&](int kb, int buf) {
    int k0 = kb * 32;
    u16* base = sm + buf * BUFE;
#pragma unroll
    for (int c = 0; c < 2; ++c) {
      int row = w * 32 + c * 16 + srow;
      int ldso = w * 1024 + c * 512;
      gload16(Ahi + (size_t)(m0 + row) * K + k0 + sc, base + ldso);
      gload16(Bhi + (size_t)(n0 + row) * K + k0 + sc, base + 4096 + ldso);
      gload16(Blo + (size_t)(n0 + row) * K + k0 + sc, base + 8192 + ldso);
    }
  };

  stage(0, 0);
  stage(1, 1);
  VMCNTN(6);
  __syncthreads();

  int cur = 0;
  for (int kb = 0; kb < nk; ++kb) {
    int stb = cur + 2;
    if (stb >= 3) stb -= 3;
    if (kb + 2 < nk) stage(kb + 2, stb);

    const u16* bs = sm + cur * BUFE;
    bf16x8 af[4], bfr[4], bfl[4];
#pragma unroll
    for (int i = 0; i < 4; ++i) {
      int swz = (g ^ ((li >> 1) & 3)) << 3;
      af[i] = *(const bf16x8*)&bs[(wr + i * 16 + li) * 32 + swz];
      bfr[i] = *(const bf16x8*)&bs[4096 + (wc + i * 16 + li) * 32 + swz];
      bfl[i] = *(const bf16x8*)&bs[8192 + (wc + i * 16 + li) * 32 + swz];
    }
#pragma unroll
    for (int a = 0; a < 4; ++a)
#pragma unroll
      for (int b = 0; b < 4; ++b) {
        acc[a][b] = MFMA16(af[a], bfr[b], acc[a][b]);
        acc[a][b] = MFMA16(af[a], bfl[b], acc[a][b]);
      }
    if (kb + 2 < nk) {
      VMCNTN(6);
    } else {
      VMCNT0();
    }
    __syncthreads();
    cur = (cur == 2) ? 0 : cur + 1;
  }

#pragma unroll
  for (int a = 0; a < 4; ++a)
#pragma unroll
    for (int b = 0; b < 4; ++b)
#pragma unroll
      for (int r = 0; r < 4; ++r) {
        int row = m0 + wr + a * 16 + g * 4 + r;
        int col = n0 + wc + b * 16 + li;
        float bb = col < 1024 ? bias[col] : bias2[col - 1024];
        float v = acc[a][b][r] + bb;
        if (col < 1024) {
          int nn = row >> 11, tt = row & 2047, kbb = tt >> 6, tr = tt & 63;
          int hq = col >> 6, d = col & 63, ks = d >> 5, dc = d & 31;
          size_t base = (((size_t)nn * 16 + hq) * 32 + kbb) * 8192;
          size_t oh = base + ks * 2048 + tr * 32 + (dc & 7) +
                      (((dc >> 3) ^ ((tr >> 1) & 3)) << 3);
          ((u16*)C0)[oh] = bf16_rtn(v);
        } else {
          int cq = col - 1024;
          float vq = v * 1.4426950408889634f;
          u16 hh, ll;
          splitf(vq, hh, ll);
          size_t off = (((size_t)(row >> 11) * 16 + (cq >> 6)) * 2048 + (row & 2047)) * 64 + (cq & 63);
          ((u16*)C1)[off] = hh;
          ((u16*)C2)[off] = ll;
        }
      }
}

// ------------- flash attention, strictly-causal + [0,0], no 1/sqrt(d) -------------
// R16-proven (51.4 us): QBLK=128, 8 waves, grid (32,16) largest-first,
// 3-buf counted vmcnt(2), unnormalized softmax, 67.5KB LDS -> 2 blocks/CU.
__global__ __launch_bounds__(512) void k_attn(
    const u16* __restrict__ Qh, const u16* __restrict__ Ql,
    const u16* __restrict__ KV, u16* __restrict__ out) {
  const int T = 2048, HD = 64, H = 16, E = 1024;
  int hc = blockIdx.x;
  int h = hc & 15, n = hc >> 4;
  int qq = 15 - (int)blockIdx.y;
  __shared__ u16 KB[3][8192];
  __shared__ u16 P[2][128][36];
  int t = threadIdx.x, lane = t & 63, w = t >> 6;
  int li = lane & 15, g = lane >> 4;

  const size_t nh = (size_t)n * H + h;
  const u16* qhb = Qh + (nh * 2048 + (size_t)qq * 128) * 64;
  const u16* qlb = Ql + (nh * 2048 + (size_t)qq * 128) * 64;
  const u16* kvb = KV + nh * 32 * 8192;

  bf16x8 qh[2], ql[2];
#pragma unroll
  for (int ks = 0; ks < 2; ++ks) {
    qh[ks] = *(const bf16x8*)&qhb[(w * 16 + li) * 64 + ks * 32 + g * 8];
    ql[ks] = *(const bf16x8*)&qlb[(w * 16 + li) * 64 + ks * 32 + g * 8];
  }

#pragma unroll
  for (int j = 0; j < 2; ++j)
    gload16(kvb + (w * 2 + j) * 512 + lane * 8, &KB[0][(w * 2 + j) * 512]);
#pragma unroll
  for (int j = 0; j < 2; ++j)
    gload16(kvb + 8192 + (w * 2 + j) * 512 + lane * 8, &KB[1][(w * 2 + j) * 512]);
  VMCNTN(2);
  __syncthreads();

  float lr[4] = {0.f, 0.f, 0.f, 0.f};
  f32x4 O[4] = {};
  int cur = 0;
  const int nkb = 2 * qq + 2;

  for (int kb = 0; kb < nkb; ++kb) {
    int stb = cur + 2;
    if (stb >= 3) stb -= 3;
    if (kb + 2 < nkb) {
      const u16* src = kvb + (size_t)(kb + 2) * 8192 + (w * 2) * 512 + lane * 8;
#pragma unroll
      for (int j = 0; j < 2; ++j)
        gload16(src + j * 512, &KB[stb][(w * 2 + j) * 512]);
    }

    f32x4 s[4] = {};
#pragma unroll
    for (int ks = 0; ks < 2; ++ks)
#pragma unroll
      for (int c = 0; c < 4; ++c) {
        int jr = c * 16 + li;
        int sw = (jr >> 1) & 3;
        bf16x8 kh = *(const bf16x8*)&KB[cur][ks * 2048 + jr * 32 + ((g ^ sw) << 3)];
        s[c] = MFMA16(qh[ks], kh, s[c]);
        s[c] = MFMA16(ql[ks], kh, s[c]);
      }

    if (kb >= 2 * qq) {
#pragma unroll
      for (int c = 0; c < 4; ++c)
#pragma unroll
        for (int r = 0; r < 4; ++r) {
          int i = qq * 128 + w * 16 + g * 4 + r;
          int j = kb * 64 + c * 16 + li;
          if (!(j < i || (i == 0 && j == 0))) s[c][r] = -INFINITY;
        }
    }

#pragma unroll
    for (int c = 0; c < 4; ++c)
#pragma unroll
      for (int r = 0; r < 4; ++r) {
        float p = exp2_hw(s[c][r]);
        s[c][r] = p;
        lr[r] += p;
      }

#pragma unroll
    for (int c = 0; c < 4; ++c)
#pragma unroll
      for (int r = 0; r < 4; ++r)
        P[c >> 1][w * 16 + g * 4 + r][(c & 1) * 16 + li] = bf16_rtn(s[c][r]);

#pragma unroll
    for (int ks = 0; ks < 2; ++ks) {
      bf16x8 pa = *(const bf16x8*)&P[ks][w * 16 + li][g * 8];
#pragma unroll
      for (int c = 0; c < 4; ++c) {
        int d = c * 16 + li;
        int tc = ks * 4 + g;
        bf16x8 vb = *(const bf16x8*)&KB[cur][4096 + d * 64 + ((tc ^ (d & 7)) << 3)];
        O[c] = MFMA16(pa, vb, O[c]);
      }
    }
    if (kb + 2 < nkb) {
      VMCNTN(2);
    } else {
      VMCNT0();
    }
    __syncthreads();
    cur = (cur == 2) ? 0 : cur + 1;
  }

#pragma unroll
  for (int off = 1; off < 16; off <<= 1)
#pragma unroll
    for (int r = 0; r < 4; ++r) lr[r] += __shfl_xor(lr[r], off, 16);

#pragma unroll
  for (int c = 0; c < 4; ++c)
#pragma unroll
    for (int r = 0; r < 4; ++r) {
      float v = O[c][r] / lr[r];
      size_t row = (size_t)n * T + qq * 128 + w * 16 + g * 4 + r;
      out[row * E + h * HD + c * 16 + li] = bf16_rtn(v);
    }
}

// ---------------------------------------------------------------------------
extern "C" void kernel_launch(void* const* d_in, const int* in_sizes, int n_in,
                              void* d_out, int out_size, void* d_ws, size_t ws_size,
                              hipStream_t stream) {
  const float* kq = (const float*)d_in[0];
  const float* v = (const float*)d_in[1];
  const float* Wk = (const float*)d_in[2];
  const float* bk = (const float*)d_in[3];
  const float* Wq = (const float*)d_in[4];
  const float* bq = (const float*)d_in[5];
  const float* Wv = (const float*)d_in[6];
  const float* bv = (const float*)d_in[7];
  const float* W1 = (const float*)d_in[8];
  const float* b1 = (const float*)d_in[9];
  const float* W2 = (const float*)d_in[10];
  const float* b2 = (const float*)d_in[11];
  float* outp = (float*)d_out;

  char* ws = (char*)d_ws;
  u16* kq_hi = (u16*)(ws + 0);
  u16* v_bf = (u16*)(ws + 8388608);
  u16* hbuf = (u16*)(ws + 0);  // 32MB, aliases kq_hi/v_bf after attention
  u16* WkqT_hi = (u16*)(ws + 33554432);  // 4MB: [WkT | WqT]
  u16* WkqT_lo = (u16*)(ws + 37748736);  // 4MB
  u16* WvT = (u16*)(ws + 41943040);
  u16* W1T = (u16*)(ws + 44040192);
  u16* W2T = (u16*)(ws + 52428800);
  u16* Qh = (u16*)(ws + 60817408);
  u16* Ql = (u16*)(ws + 69206016);
  u16* KV = (u16*)(ws + 77594624);  // 16MB: 1024 slabs x 16KB (K hi + V)
  u16* attn_o = (u16*)(ws + 102760448);
  // total: 111,149,056 bytes

  // --- all prep in ONE launch (cvt + 5 weight transposes) ---
  k_prep<<<19456, 256, 0, stream>>>(kq, v, Wk, Wq, Wv, W1, W2, kq_hi, v_bf,
                                    WkqT_hi, WkqT_lo, WvT, W1T, W2T);

  // --- fused K|Q projection (2-pass split, 3-buf counted vmcnt, XCD swz) ---
  k_gemm_s<<<dim3(16, 32), 256, 0, stream>>>(
      kq_hi, WkqT_hi, WkqT_lo, bk, bq, KV, Qh, Ql, 4096, 2048, 1024);
  // --- V projection ---
  k_gemm<0, 5, 64><<<dim3(16, 32), 256, 0, stream>>>(
      v_bf, WvT, bv, KV, 4096, 1024, 1024);

  // --- attention (R16-proven) ---
  k_attn<<<dim3(32, 16), 512, 0, stream>>>(Qh, Ql, KV, attn_o);

  // --- FFN ---
  k_gemm2<1, 1><<<dim3(16, 16), 512, 0, stream>>>(
      attn_o, W1T, b1, hbuf, 4096, 4096, 1024);
  k_gemm<0, 0, 128><<<dim3(8, 32), 256, 0, stream>>>(
      hbuf, W2T, b2, outp, 4096, 1024, 4096);
}